// Round 7
// baseline (7303.065 us; speedup 1.0000x reference)
//
#include <hip/hip_runtime.h>
#include <hip/hip_bf16.h>
#include <math.h>

#define NN 118
#define TT 2048
#define NF 64
#define DP 128
#define DN 256

typedef float v2f __attribute__((ext_vector_type(2)));

__device__ __forceinline__ float leaky(float x) { return x > 0.f ? x : 0.01f * x; }

__device__ __forceinline__ float waveRedSum(float v) {
#pragma unroll
    for (int off = 32; off > 0; off >>= 1) v += __shfl_down(v, off, 64);
    return v;
}
__device__ __forceinline__ float waveRedMax(float v) {
#pragma unroll
    for (int off = 32; off > 0; off >>= 1) v = fmaxf(v, __shfl_down(v, off, 64));
    return v;
}

__device__ __forceinline__ float sigmoidf_(float x) { return 1.0f / (1.0f + __expf(-x)); }
__device__ __forceinline__ float tanhf_(float x) { return 1.0f - 2.0f / (__expf(2.0f * x) + 1.0f); }

// sum across the 4 lanes of a quad via DPP quad_perm (VALU pipe, no LDS traffic)
__device__ __forceinline__ float quad_sum(float v) {
    v += __int_as_float(__builtin_amdgcn_mov_dpp(__float_as_int(v), 0xB1, 0xF, 0xF, true)); // xor 1
    v += __int_as_float(__builtin_amdgcn_mov_dpp(__float_as_int(v), 0x4E, 0xF, 0xF, true)); // xor 2
    return v;
}

// ---------------- GEMM v2: out[M,512] = A[M,KK] @ W[512,KK]^T + (b1+b2) ------------
// 128x128 tile, 256 threads, 8x8 micro-tile, K staged in 32-wide LDS chunks.
// Row stride 36 floats: As reads (4 distinct ty/wave) hit banks {0,4,8,12} quads
// (conflict-free); Bs reads (16 tx) are 2-way aliased = free (m136). VALU-bound:
// per kk DS 16xb128 (~192cyc) vs 512 FMA-cyc.
template <int KK>
__global__ __launch_bounds__(256) void xg_gemm2(
    const float* __restrict__ A, const float* __restrict__ W,
    const float* __restrict__ b1, const float* __restrict__ b2,
    float* __restrict__ out, int rowStride, int rowOff, int lgTc) {
    int m0 = blockIdx.x * 128, n0 = blockIdx.y * 128;
    int tid = threadIdx.x, tx = tid & 15, ty = tid >> 4;
    __shared__ __align__(16) float As[128][36];
    __shared__ __align__(16) float Bs[128][36];
    float acc[8][8] = {};
    int Tcm = (1 << lgTc) - 1;
    int lr = tid >> 3, lc = (tid & 7) * 4;
    for (int k0 = 0; k0 < KK; k0 += 32) {
        __syncthreads();
#pragma unroll
        for (int r = 0; r < 4; r++) {
            int mm = r * 32 + lr;
            int m = m0 + mm;
            int gr = ((m >> lgTc) * rowStride) + (m & Tcm) + rowOff;
            *(float4*)&As[mm][lc] = *(const float4*)&A[(size_t)gr * KK + k0 + lc];
            *(float4*)&Bs[mm][lc] = *(const float4*)&W[(size_t)(n0 + mm) * KK + k0 + lc];
        }
        __syncthreads();
#pragma unroll
        for (int kk = 0; kk < 8; kk++) {
            float4 a4[8];
#pragma unroll
            for (int ii = 0; ii < 8; ii++) a4[ii] = *(const float4*)&As[ty + 16 * ii][4 * kk];
#pragma unroll
            for (int jj = 0; jj < 8; jj++) {
                float4 b = *(const float4*)&Bs[tx + 16 * jj][4 * kk];
#pragma unroll
                for (int ii = 0; ii < 8; ii++)
                    acc[ii][jj] += a4[ii].x * b.x + a4[ii].y * b.y +
                                   a4[ii].z * b.z + a4[ii].w * b.w;
            }
        }
    }
#pragma unroll
    for (int jj = 0; jj < 8; jj++) {
        int col = n0 + tx + 16 * jj;
        float bb = b1[col] + b2[col];
#pragma unroll
        for (int ii = 0; ii < 8; ii++)
            out[(size_t)(m0 + ty + 16 * ii) * 512 + col] = acc[ii][jj] + bb;
    }
}

// ---------------- Pipelined 2-layer LSTM recurrence --------------------------------
// grid (NN, 2): layer 0 chunk p, layer 1 chunk p-1. 512 threads: (unit g = t>>2,
// K-quarter kq = t&3); 128 weight floats per thread as 64 named v2f values.
// KEY FIX (R7): KEEP must be asm VOLATILE. R6's non-volatile empty asm is
// side-effect-free -> legal to sink/duplicate into the loop with its load chain,
// so weights were re-read from global (L2-hit) every step (VGPR_Count stuck at 88,
// FETCH flat). Volatile asm cannot be moved/duplicated -> weights materialize once
// and must stay live (budget 256 @ waves_per_eu(2,2)) or truly spill (visible).
#define LOADW(r, j) \
    float4 t##r##_##j = *(const float4*)&Whh[(size_t)(g + 128 * (r)) * 128 + kq * 32 + 4 * (j)]; \
    v2f w##r##_##j##a = {t##r##_##j.x, t##r##_##j.y}; \
    v2f w##r##_##j##b = {t##r##_##j.z, t##r##_##j.w};
#define LOADW_R(r) LOADW(r, 0) LOADW(r, 1) LOADW(r, 2) LOADW(r, 3) \
                   LOADW(r, 4) LOADW(r, 5) LOADW(r, 6) LOADW(r, 7)
#define KEEP(x) asm volatile("" : "+v"(x));
#define KEEPW(r, j) KEEP(w##r##_##j##a) KEEP(w##r##_##j##b)
#define KEEPW_R(r) KEEPW(r, 0) KEEPW(r, 1) KEEPW(r, 2) KEEPW(r, 3) \
                   KEEPW(r, 4) KEEPW(r, 5) KEEPW(r, 6) KEEPW(r, 7)
#define DOTJ(j) { \
    float4 hv4 = h4[j]; \
    v2f hl = {hv4.x, hv4.y}; v2f hh = {hv4.z, hv4.w}; \
    acc0 += w0_##j##a * hl; acc0 += w0_##j##b * hh; \
    acc1 += w1_##j##a * hl; acc1 += w1_##j##b * hh; \
    acc2 += w2_##j##a * hl; acc2 += w2_##j##b * hh; \
    acc3 += w3_##j##a * hl; acc3 += w3_##j##b * hh; }

__global__ void
__attribute__((amdgpu_flat_work_group_size(512, 512), amdgpu_waves_per_eu(2, 2)))
lstm2_rec(
    const float* __restrict__ xg0, const float* __restrict__ xg1,
    const float* __restrict__ Whh0, const float* __restrict__ Whh1,
    float* __restrict__ h0s, float* __restrict__ c0s,
    float* __restrict__ h1s, float* __restrict__ c1s,
    float* __restrict__ h1c, float* __restrict__ p_out,
    int phase, int nch, int Tc) {
    int layer = blockIdx.y;
    if (layer == 0 && phase >= nch) return;
    if (layer == 1 && phase == 0) return;
    const float* __restrict__ xg  = layer ? xg1 : xg0;
    const float* __restrict__ Whh = layer ? Whh1 : Whh0;
    float* hs = layer ? h1s : h0s;
    float* cs = layer ? c1s : c0s;
    int t_start = (layer ? (phase - 1) : phase) * Tc;

    int b = blockIdx.x, t = threadIdx.x;
    int g = t >> 2, kq = t & 3;
    __shared__ __align__(16) float hb[2][160];   // 4 quarters x 36-float swizzled rows

    LOADW_R(0) LOADW_R(1) LOADW_R(2) LOADW_R(3)
    KEEPW_R(0) KEEPW_R(1) KEEPW_R(2) KEEPW_R(3)

    float c = 0.f;
    float xc0 = 0.f, xc1 = 0.f, xc2 = 0.f, xc3 = 0.f;
    const float* xgb = xg + (size_t)b * Tc * 512;
    if (kq == 0) {
        c = cs[b * 128 + g];
        xc0 = xgb[g]; xc1 = xgb[g + 128]; xc2 = xgb[g + 256]; xc3 = xgb[g + 384];
    }
    if (t < 128) hb[0][(t >> 5) * 36 + (t & 31)] = hs[b * 128 + t];
    __syncthreads();

    int cur = 0;
    float h = 0.f;
#pragma unroll 1
    for (int tl = 0; tl < Tc; tl++) {
        float xn0 = 0.f, xn1 = 0.f, xn2 = 0.f, xn3 = 0.f;
        if (kq == 0 && tl + 1 < Tc) {
            const float* xr = &xgb[(size_t)(tl + 1) * 512];
            xn0 = xr[g]; xn1 = xr[g + 128]; xn2 = xr[g + 256]; xn3 = xr[g + 384];
        }
        v2f acc0 = {0.f, 0.f}, acc1 = {0.f, 0.f}, acc2 = {0.f, 0.f}, acc3 = {0.f, 0.f};
        const float4* h4 = (const float4*)&hb[cur][kq * 36];
        DOTJ(0) DOTJ(1) DOTJ(2) DOTJ(3) DOTJ(4) DOTJ(5) DOTJ(6) DOTJ(7)
        float a0 = quad_sum(acc0.x + acc0.y);
        float a1 = quad_sum(acc1.x + acc1.y);
        float a2 = quad_sum(acc2.x + acc2.y);
        float a3 = quad_sum(acc3.x + acc3.y);
        if (kq == 0) {
            float gi = a0 + xc0, gf = a1 + xc1, gg = a2 + xc2, go = a3 + xc3;
            c = sigmoidf_(gf) * c + sigmoidf_(gi) * tanhf_(gg);
            h = sigmoidf_(go) * tanhf_(c);
            hb[cur ^ 1][(g >> 5) * 36 + (g & 31)] = h;
            if (layer == 0) {
                h1c[(size_t)(b * Tc + tl) * 128 + g] = h;
            } else if (t_start + tl == TT - 1) {
                p_out[b * 128 + g] = leaky(h);
            }
            xc0 = xn0; xc1 = xn1; xc2 = xn2; xc3 = xn3;
        }
        __syncthreads();
        cur ^= 1;
    }
    if (kq == 0) { cs[b * 128 + g] = c; hs[b * 128 + g] = h; }
}

// ---------------- Head part 1: per-row i, everything up to n + precomputes ---------
__global__ __launch_bounds__(256) void head1_kernel(
    const float* __restrict__ x_message, const float* __restrict__ pseudo,
    const float* __restrict__ p_out,
    const float* __restrict__ Wum, const float* __restrict__ Wvm,
    const float* __restrict__ Wup, const float* __restrict__ Wvp,
    const float* __restrict__ Wpe, const float* __restrict__ bpe,
    const float* __restrict__ Whyb, const float* __restrict__ bhyb,
    const float* __restrict__ Wact, const float* __restrict__ bact,
    const float* __restrict__ Winact, const float* __restrict__ binact,
    const float* __restrict__ Wphin, const float* __restrict__ Won,
    const float* __restrict__ Weo,
    float* __restrict__ st_out, float* __restrict__ n_out, float* __restrict__ wnn_out,
    float* __restrict__ R_out, float* __restrict__ S_out,
    float* __restrict__ P_out, float* __restrict__ Q_out,
    float* __restrict__ A_out, float* __restrict__ B_out,
    float* __restrict__ d_out) {
    int i = blockIdx.x, tid = threadIdx.x;
    __shared__ float mc[769];
    __shared__ float pcp[128];
    __shared__ float um[128], vm[128], up[128], vp[128];
    __shared__ float hyb[256], nsh[256];
    __shared__ float red[4];
    __shared__ float sred[2][2];
    __shared__ float st_sh, hp0_sh, hp1_sh, wpol_sh, norm_sh;

    float s = 0.f;
    for (int q = tid; q < 768; q += 256) s += x_message[i * 768 + q];
    s = waveRedSum(s);
    if ((tid & 63) == 0) red[tid >> 6] = s;
    __syncthreads();
    if (tid == 0) {
        float tot = red[0] + red[1] + red[2] + red[3];
        float st = (tot == 0.f) ? 1.f : 0.f;
        st_sh = st; st_out[i] = st;
    }
    __syncthreads();
    float st = st_sh;
    for (int q = tid; q < 768; q += 256)
        mc[q] = (st == 1.f) ? pseudo[q] : x_message[i * 768 + q];
    if (tid == 0) mc[768] = st;
    if (tid < 128) pcp[tid] = p_out[i * 128 + tid];
    __syncthreads();

    if (tid < 128) {
        int d = tid;
        float a0 = 0.f;
        for (int q = 0; q < 769; q++) a0 += mc[q] * Wum[q * 128 + d];
        um[d] = leaky(a0);
        float a1 = 0.f;
        for (int q = 0; q < 128; q++) a1 += pcp[q] * Wup[q * 128 + d];
        a1 += st * Wup[128 * 128 + d];
        up[d] = leaky(a1);
    } else {
        int d = tid - 128;
        float a0 = 0.f;
        for (int q = 0; q < 769; q++) a0 += mc[q] * Wvm[q * 128 + d];
        vm[d] = leaky(a0);
        float a1 = 0.f;
        for (int q = 0; q < 128; q++) a1 += pcp[q] * Wvp[q * 128 + d];
        a1 += st * Wvp[128 * 128 + d];
        vp[d] = leaky(a1);
    }
    __syncthreads();

    float t0 = 0.f, t1 = 0.f;
    if (tid < 128) {
        int d = tid;
        float um_d = um[d], vp_d = vp[d], uv = um_d * vp_d;
        t0 = um_d * Wpe[d] + uv * Wpe[128 + d] + vp_d * Wpe[256 + d];
        t1 = um_d * Wpe[384 + d] + uv * Wpe[384 + 128 + d] + vp_d * Wpe[384 + 256 + d];
    }
    t0 = waveRedSum(t0); t1 = waveRedSum(t1);
    if (tid < 128 && (tid & 63) == 0) { sred[0][tid >> 6] = t0; sred[1][tid >> 6] = t1; }
    __syncthreads();
    if (tid == 0) {
        float z0 = sred[0][0] + sred[0][1] + bpe[0];
        float z1 = sred[1][0] + sred[1][1] + bpe[1];
        float mx = fmaxf(z0, z1);
        float e0 = __expf(z0 - mx), e1 = __expf(z1 - mx);
        float inv = 1.f / (e0 + e1);
        float h0 = e0 * inv, h1 = e1 * inv;
        d_out[236 + i * 2 + 0] = h0; d_out[236 + i * 2 + 1] = h1;
        hp0_sh = h0; hp1_sh = h1;
        float sgn = (z1 > z0) ? 1.f : ((z1 < z0) ? -1.f : 0.f);
        wpol_sh = (st == 0.f) ? sgn : 0.f;
    }
    __syncthreads();

    {
        float acc = bhyb[tid];
        const float* Wr = Whyb + tid * 384;
        for (int q = 0; q < 128; q++) {
            float upq = up[q], vmq = vm[q];
            acc += upq * Wr[q] + (upq + vmq) * Wr[128 + q] + vmq * Wr[256 + q];
        }
        hyb[tid] = leaky(acc);
    }
    __syncthreads();

    {
        float hp0 = hp0_sh, hp1 = hp1_sh;
        float aa = bact[tid];
        float ai = binact[tid];
        const float* Wr = Wact + tid * 258;
        const float* Wr2 = Winact + tid * 256;
        for (int q = 0; q < 256; q++) { float h = hyb[q]; aa += h * Wr[q]; ai += h * Wr2[q]; }
        aa += hp0 * Wr[256] + hp1 * Wr[257];
        float nv = leaky(aa * (1.f - st) + ai * st);
        nsh[tid] = nv; n_out[i * 256 + tid] = nv;
    }
    __syncthreads();

    float nv = nsh[tid];
    float ssum = waveRedSum(nv * nv);
    if ((tid & 63) == 0) red[tid >> 6] = ssum;
    __syncthreads();
    if (tid == 0) norm_sh = fmaxf(sqrtf(red[0] + red[1] + red[2] + red[3]), 1e-8f);
    __syncthreads();
    wnn_out[i * 256 + tid] = wpol_sh * nv / norm_sh;

    if (tid < 192) {
        float r = 0.f, sc = 0.f;
        for (int q = 0; q < 256; q++) {
            float nq = nsh[q];
            r += nq * Wphin[q * 192 + tid];
            sc += nq * Wphin[(256 + q) * 192 + tid];
        }
        R_out[i * 192 + tid] = r; S_out[i * 192 + tid] = sc;
    }
    {
        float pa = 0.f, qa = 0.f, aa = 0.f, ba = 0.f;
        for (int q = 0; q < 256; q++) {
            float nq = nsh[q];
            pa += nq * Won[q * 256 + tid];
            qa += nq * Won[(256 + q) * 256 + tid];
            aa += nq * Weo[(256 + q) * 256 + tid];
            ba += nq * Weo[(512 + q) * 256 + tid];
        }
        P_out[i * 256 + tid] = pa; Q_out[i * 256 + tid] = qa;
        A_out[i * 256 + tid] = aa; B_out[i * 256 + tid] = ba;
    }
}

// ---------------- l_ort via Gram trick --------------------------------------------
__global__ __launch_bounds__(128) void lort_kernel(
    const float* __restrict__ Wum, const float* __restrict__ Wvm,
    const float* __restrict__ Wup, const float* __restrict__ Wvp,
    float* __restrict__ lort) {
    int k = blockIdx.x, l = threadIdx.x, which = blockIdx.y;
    const float* Am = which ? Wup : Wum;
    const float* Bm = which ? Wvp : Wvm;
    int Rr = which ? 129 : 769;
    float g1 = 0.f, g2 = 0.f;
    for (int m = 0; m < Rr; m++) {
        g1 += Am[m * 128 + k] * Am[m * 128 + l];
        g2 += Bm[m * 128 + k] * Bm[m * 128 + l];
    }
    float p = waveRedSum(g1 * g2);
    if ((l & 63) == 0) atomicAdd(&lort[which], p);
}

// ---------------- phi(i,j) = leaky(R[j]+S[i]) . aphi  (stored column-major) --------
__global__ __launch_bounds__(128) void phi_kernel(
    const float* __restrict__ R, const float* __restrict__ S,
    const float* __restrict__ aphi, float* __restrict__ phi_cm) {
    int j = blockIdx.x, tid = threadIdx.x;
    __shared__ float rj[192], ap[192];
    for (int q = tid; q < 192; q += 128) { rj[q] = R[j * 192 + q]; ap[q] = aphi[q]; }
    __syncthreads();
    if (tid < NN) {
        const float* Si = S + tid * 192;
        float acc = 0.f;
        for (int d = 0; d < 192; d++) acc += leaky(rj[d] + Si[d]) * ap[d];
        phi_cm[j * NN + tid] = acc;
    }
}

// ---------------- double group-softmax over rows, per column ----------------------
__global__ __launch_bounds__(128) void alpha_kernel(
    const float* __restrict__ phi_cm, const float* __restrict__ stv,
    float* __restrict__ w0_cm, float* __restrict__ w1_cm) {
    int j = blockIdx.x, tid = threadIdx.x;
    __shared__ float sm[2][2], ssum[2][2];
    bool act = tid < NN;
    float sti = act ? stv[tid] : -1.f;
    float v = act ? phi_cm[j * NN + tid] : 0.f;
    float m0 = (sti == 0.f) ? v : -3.0e38f;
    float m1 = (sti == 1.f) ? v : -3.0e38f;
    float M0 = waveRedMax(m0), M1 = waveRedMax(m1);
    if ((tid & 63) == 0) { sm[tid >> 6][0] = M0; sm[tid >> 6][1] = M1; }
    __syncthreads();
    M0 = fmaxf(sm[0][0], sm[1][0]); M1 = fmaxf(sm[0][1], sm[1][1]);
    float e = 0.f;
    if (act) e = __expf(v - ((sti == 0.f) ? M0 : M1));
    float e0 = (sti == 0.f) ? e : 0.f, e1 = (sti == 1.f) ? e : 0.f;
    float S0 = waveRedSum(e0), S1 = waveRedSum(e1);
    if ((tid & 63) == 0) { ssum[tid >> 6][0] = S0; ssum[tid >> 6][1] = S1; }
    __syncthreads();
    S0 = ssum[0][0] + ssum[1][0]; S1 = ssum[0][1] + ssum[1][1];
    if (act) {
        float alpha = e / ((sti == 0.f) ? S0 : S1);
        w0_cm[j * NN + tid] = sti * alpha;
        w1_cm[j * NN + tid] = (1.f - sti) * alpha;
    }
}

// ---------------- per-row weighted sums over j ------------------------------------
__global__ __launch_bounds__(256) void qsum_kernel(
    const float* __restrict__ P, const float* __restrict__ Q, const float* __restrict__ Ab,
    const float* __restrict__ w0_cm, const float* __restrict__ w1_cm,
    float* __restrict__ qs0, float* __restrict__ qs1,
    float* __restrict__ as0, float* __restrict__ as1,
    float* __restrict__ ws0, float* __restrict__ ws1) {
    int i = blockIdx.x, d = threadIdx.x;
    float Qd = Q[i * 256 + d];
    float q0 = 0.f, q1 = 0.f, a0 = 0.f, a1 = 0.f, s0 = 0.f, s1 = 0.f;
    for (int jj = 0; jj < NN; jj++) {
        float w0 = w0_cm[jj * NN + i], w1 = w1_cm[jj * NN + i];
        float pq = leaky(P[jj * 256 + d] + Qd);
        float av = Ab[jj * 256 + d];
        q0 += w0 * pq; q1 += w1 * pq;
        a0 += w0 * av; a1 += w1 * av;
        s0 += w0; s1 += w1;
    }
    qs0[i * 256 + d] = q0; qs1[i * 256 + d] = q1;
    as0[i * 256 + d] = a0; as1[i * 256 + d] = a1;
    if (d == 0) { ws0[i] = s0; ws1[i] = s1; }
}

// ---------------- hm0/hm1, output head, y_hat -------------------------------------
__global__ __launch_bounds__(256) void hm_out_kernel(
    const float* __restrict__ qs0, const float* __restrict__ qs1,
    const float* __restrict__ as0, const float* __restrict__ as1,
    const float* __restrict__ ws0, const float* __restrict__ ws1,
    const float* __restrict__ Bb, const float* __restrict__ nbuf,
    const float* __restrict__ Weo, const float* __restrict__ Wi,
    const float* __restrict__ bi, float* __restrict__ d_out) {
    int i = blockIdx.x, d = threadIdx.x;
    __shared__ float q0sh[256], q1sh[256];
    __shared__ float r0[4], r1[4];
    q0sh[d] = qs0[i * 256 + d]; q1sh[d] = qs1[i * 256 + d];
    __syncthreads();
    float Bd = Bb[i * 256 + d];
    float h0 = as0[i * 256 + d] + ws0[i] * Bd;
    float h1 = as1[i * 256 + d] + ws1[i] * Bd;
    for (int k = 0; k < 256; k++) {
        float w = Weo[k * 256 + d];
        h0 += q0sh[k] * w; h1 += q1sh[k] * w;
    }
    h0 = leaky(h0); h1 = leaky(h1);
    float nd = nbuf[i * 256 + d];
    const float* Wii = Wi + (size_t)i * 1536;
    float l0 = nd * Wii[d * 2] + h0 * Wii[(256 + d) * 2] + h1 * Wii[(512 + d) * 2];
    float l1 = nd * Wii[d * 2 + 1] + h0 * Wii[(256 + d) * 2 + 1] + h1 * Wii[(512 + d) * 2 + 1];
    l0 = waveRedSum(l0); l1 = waveRedSum(l1);
    if ((d & 63) == 0) { r0[d >> 6] = l0; r1[d >> 6] = l1; }
    __syncthreads();
    if (d == 0) {
        float z0 = r0[0] + r0[1] + r0[2] + r0[3] + bi[i * 2 + 0];
        float z1 = r1[0] + r1[1] + r1[2] + r1[3] + bi[i * 2 + 1];
        float mx = fmaxf(z0, z1);
        float e0 = __expf(z0 - mx), e1 = __expf(z1 - mx);
        float inv = 1.f / (e0 + e1);
        d_out[i * 2 + 0] = e0 * inv;
        d_out[i * 2 + 1] = e1 * inv;
    }
}

// ---------------- l_pol + l_ort finalize ------------------------------------------
__global__ __launch_bounds__(256) void pol_kernel(
    const float* __restrict__ wnn, const float* __restrict__ lort,
    float* __restrict__ d_out) {
    int d = threadIdx.x;
    __shared__ float red[4];
    float s = 0.f;
    for (int i = 0; i < NN; i++) s += wnn[i * 256 + d];
    float p = waveRedSum(s * s);
    if ((d & 63) == 0) red[d >> 6] = p;
    __syncthreads();
    if (d == 0) {
        d_out[473] = red[0] + red[1] + red[2] + red[3];
        d_out[472] = sqrtf(lort[0]) + sqrtf(lort[1]);
    }
}

extern "C" void kernel_launch(void* const* d_in, const int* in_sizes, int n_in,
                              void* d_out_v, int out_size, void* d_ws, size_t ws_size,
                              hipStream_t stream) {
    (void)in_sizes; (void)n_in; (void)out_size;
    const float* x        = (const float*)d_in[0];
    const float* x_msg    = (const float*)d_in[1];
    const float* pseudo   = (const float*)d_in[2];
    const float* Wih0     = (const float*)d_in[3];
    const float* Whh0     = (const float*)d_in[4];
    const float* bih0     = (const float*)d_in[5];
    const float* bhh0     = (const float*)d_in[6];
    const float* Wih1     = (const float*)d_in[7];
    const float* Whh1     = (const float*)d_in[8];
    const float* bih1     = (const float*)d_in[9];
    const float* bhh1     = (const float*)d_in[10];
    const float* Wum      = (const float*)d_in[11];
    const float* Wvm      = (const float*)d_in[12];
    const float* Wup      = (const float*)d_in[13];
    const float* Wvp      = (const float*)d_in[14];
    const float* Wpe      = (const float*)d_in[15];
    const float* bpe      = (const float*)d_in[16];
    const float* Whyb     = (const float*)d_in[17];
    const float* bhyb     = (const float*)d_in[18];
    const float* Wact     = (const float*)d_in[19];
    const float* bact     = (const float*)d_in[20];
    const float* Winact   = (const float*)d_in[21];
    const float* binact   = (const float*)d_in[22];
    const float* Wphin    = (const float*)d_in[23];
    const float* aphi     = (const float*)d_in[24];
    const float* Won      = (const float*)d_in[25];
    const float* Weo      = (const float*)d_in[26];
    const float* Wi       = (const float*)d_in[27];
    const float* bi       = (const float*)d_in[28];
    float* out = (float*)d_out_v;

    char* wsb = (char*)d_ws;
    size_t off = 0;
    auto alloc = [&](size_t nfloats) {
        float* p = (float*)(wsb + off);
        off += ((nfloats * 4 + 255) / 256) * 256;
        return p;
    };
    float* h0s   = alloc(NN * 128);
    float* c0s   = alloc(NN * 128);
    float* h1s   = alloc(NN * 128);
    float* c1s   = alloc(NN * 128);
    float* lort  = alloc(2);
    float* stb   = alloc(NN);
    float* p_out = alloc(NN * 128);
    float* nbuf  = alloc(NN * 256);
    float* wnn   = alloc(NN * 256);
    float* Rb    = alloc(NN * 192);
    float* Sb    = alloc(NN * 192);
    float* Pb    = alloc(NN * 256);
    float* Qb    = alloc(NN * 256);
    float* Ab    = alloc(NN * 256);
    float* Bb    = alloc(NN * 256);
    float* qs0   = alloc(NN * 256);
    float* qs1   = alloc(NN * 256);
    float* as0   = alloc(NN * 256);
    float* as1   = alloc(NN * 256);
    float* ws0   = alloc(NN);
    float* ws1   = alloc(NN);
    float* phicm = alloc(NN * NN);
    float* w0cm  = alloc(NN * NN);
    float* w1cm  = alloc(NN * NN);

    size_t remain = (ws_size > off) ? (ws_size - off) : 0;
    int Tc = 2048;
    // need xg0 + xg1 (NN*Tc*512 each) + h1c (NN*Tc*128)
    while (Tc > 64 && (size_t)NN * Tc * (512 + 512 + 128) * 4 > remain) Tc >>= 1;
    float* xg0 = alloc((size_t)NN * Tc * 512);
    float* xg1 = alloc((size_t)NN * Tc * 512);
    float* h1c = alloc((size_t)NN * Tc * 128);
    int lgTc = __builtin_ctz(Tc);

    hipMemsetAsync(h0s, 0, (size_t)4 * NN * 128 * sizeof(float), stream); // h0s..c1s contiguous
    hipMemsetAsync(lort, 0, 2 * sizeof(float), stream);

    int nch = TT / Tc;
    dim3 gg((NN * Tc) / 128, 4);
    // prologue: xg0 for chunk 0
    xg_gemm2<64><<<gg, 256, 0, stream>>>(x, Wih0, bih0, bhh0, xg0, TT, 0, lgTc);
    for (int p = 0; p <= nch; p++) {
        lstm2_rec<<<dim3(NN, 2), 512, 0, stream>>>(xg0, xg1, Whh0, Whh1,
                                                   h0s, c0s, h1s, c1s,
                                                   h1c, p_out, p, nch, Tc);
        if (p < nch)
            xg_gemm2<128><<<gg, 256, 0, stream>>>(h1c, Wih1, bih1, bhh1, xg1, Tc, 0, lgTc);
        if (p + 1 < nch)
            xg_gemm2<64><<<gg, 256, 0, stream>>>(x, Wih0, bih0, bhh0, xg0, TT, (p + 1) * Tc, lgTc);
    }
    head1_kernel<<<NN, 256, 0, stream>>>(x_msg, pseudo, p_out, Wum, Wvm, Wup, Wvp,
                                         Wpe, bpe, Whyb, bhyb, Wact, bact, Winact, binact,
                                         Wphin, Won, Weo,
                                         stb, nbuf, wnn, Rb, Sb, Pb, Qb, Ab, Bb, out);
    lort_kernel<<<dim3(128, 2), 128, 0, stream>>>(Wum, Wvm, Wup, Wvp, lort);
    phi_kernel<<<NN, 128, 0, stream>>>(Rb, Sb, aphi, phicm);
    alpha_kernel<<<NN, 128, 0, stream>>>(phicm, stb, w0cm, w1cm);
    qsum_kernel<<<NN, 256, 0, stream>>>(Pb, Qb, Ab, w0cm, w1cm, qs0, qs1, as0, as1, ws0, ws1);
    hm_out_kernel<<<NN, 256, 0, stream>>>(qs0, qs1, as0, as1, ws0, ws1, Bb, nbuf, Weo, Wi, bi, out);
    pol_kernel<<<1, 256, 0, stream>>>(wnn, lort, out);
}

// Round 8
// 3289.380 us; speedup vs baseline: 2.2202x; 2.2202x over previous
//
#include <hip/hip_runtime.h>
#include <hip/hip_bf16.h>
#include <math.h>

#define NN 118
#define TT 2048
#define NF 64
#define DP 128
#define DN 256

typedef float v2f __attribute__((ext_vector_type(2)));

__device__ __forceinline__ float leaky(float x) { return x > 0.f ? x : 0.01f * x; }

__device__ __forceinline__ float waveRedSum(float v) {
#pragma unroll
    for (int off = 32; off > 0; off >>= 1) v += __shfl_down(v, off, 64);
    return v;
}
__device__ __forceinline__ float waveRedMax(float v) {
#pragma unroll
    for (int off = 32; off > 0; off >>= 1) v = fmaxf(v, __shfl_down(v, off, 64));
    return v;
}

__device__ __forceinline__ float sigmoidf_(float x) { return 1.0f / (1.0f + __expf(-x)); }
__device__ __forceinline__ float tanhf_(float x) { return 1.0f - 2.0f / (__expf(2.0f * x) + 1.0f); }

// sum across the 4 lanes of a quad via DPP quad_perm (VALU pipe, no LDS traffic)
__device__ __forceinline__ float quad_sum(float v) {
    v += __int_as_float(__builtin_amdgcn_mov_dpp(__float_as_int(v), 0xB1, 0xF, 0xF, true)); // xor 1
    v += __int_as_float(__builtin_amdgcn_mov_dpp(__float_as_int(v), 0x4E, 0xF, 0xF, true)); // xor 2
    return v;
}

// ---------------- GEMM: out[M,512] = A[M,KK] @ W[512,KK]^T + (b1+b2) ---------------
// R8: reverted to the R6-proven 64x64/4x4 version. R7's 128x128/8x8 rewrite maxed
// VGPRs (256) and spilled the ACCUMULATORS -> 1.25 GB HBM scratch traffic/dispatch,
// 412 us each (7.4x regression). acc 4x4 + a4/b4 float4s fits comfortably.
template <int KK>
__global__ __launch_bounds__(256) void xg_gemm(
    const float* __restrict__ A, const float* __restrict__ W,
    const float* __restrict__ b1, const float* __restrict__ b2,
    float* __restrict__ out, int rowStride, int rowOff, int lgTc) {
    int m0 = blockIdx.x * 64, n0 = blockIdx.y * 64;
    int tid = threadIdx.x, tx = tid & 15, ty = tid >> 4;
    __shared__ __align__(16) float As[64][KK + 4];
    __shared__ __align__(16) float Bs[64][KK + 4];
    const int SL = KK / 4;
    const int NL = 64 * SL / 256;
    int Tcm = (1 << lgTc) - 1;
#pragma unroll
    for (int r = 0; r < NL; r++) {
        int f = r * 256 + tid;
        int mm = f / SL, kv = f % SL;
        int m = m0 + mm;
        int grow = (m >> lgTc) * rowStride + (m & Tcm) + rowOff;
        *(float4*)&As[mm][4 * kv] = *(const float4*)&A[(size_t)grow * KK + 4 * kv];
        *(float4*)&Bs[mm][4 * kv] = *(const float4*)&W[(size_t)(n0 + mm) * KK + 4 * kv];
    }
    __syncthreads();
    float acc[4][4] = {};
#pragma unroll 4
    for (int kk = 0; kk < SL; kk++) {
        float4 a4[4], b4[4];
#pragma unroll
        for (int i = 0; i < 4; i++) a4[i] = *(const float4*)&As[4 * ty + i][4 * kk];
#pragma unroll
        for (int i = 0; i < 4; i++) b4[i] = *(const float4*)&Bs[tx + 16 * i][4 * kk];
#pragma unroll
        for (int i = 0; i < 4; i++)
#pragma unroll
            for (int jj = 0; jj < 4; jj++)
                acc[i][jj] += a4[i].x * b4[jj].x + a4[i].y * b4[jj].y +
                              a4[i].z * b4[jj].z + a4[i].w * b4[jj].w;
    }
#pragma unroll
    for (int jj = 0; jj < 4; jj++) {
        int col = n0 + tx + 16 * jj;
        float bb = b1[col] + b2[col];
#pragma unroll
        for (int i = 0; i < 4; i++) {
            size_t row = m0 + 4 * ty + i;
            out[row * 512 + col] = acc[i][jj] + bb;
        }
    }
}

// ---------------- Pipelined 2-layer LSTM recurrence --------------------------------
// grid (NN, 2): layer 0 chunk p, layer 1 chunk p-1. 512 threads: (unit g = t>>2,
// K-quarter kq = t&3); 128 weight floats per thread as 64 named v2f values,
// pinned with volatile asm (cannot be sunk/duplicated -> must stay live or truly
// spill). waves_per_eu(2,2) gives the full 256-VGPR budget.
#define LOADW(r, j) \
    float4 t##r##_##j = *(const float4*)&Whh[(size_t)(g + 128 * (r)) * 128 + kq * 32 + 4 * (j)]; \
    v2f w##r##_##j##a = {t##r##_##j.x, t##r##_##j.y}; \
    v2f w##r##_##j##b = {t##r##_##j.z, t##r##_##j.w};
#define LOADW_R(r) LOADW(r, 0) LOADW(r, 1) LOADW(r, 2) LOADW(r, 3) \
                   LOADW(r, 4) LOADW(r, 5) LOADW(r, 6) LOADW(r, 7)
#define KEEP(x) asm volatile("" : "+v"(x));
#define KEEPW(r, j) KEEP(w##r##_##j##a) KEEP(w##r##_##j##b)
#define KEEPW_R(r) KEEPW(r, 0) KEEPW(r, 1) KEEPW(r, 2) KEEPW(r, 3) \
                   KEEPW(r, 4) KEEPW(r, 5) KEEPW(r, 6) KEEPW(r, 7)
#define DOTJ(j) { \
    float4 hv4 = h4[j]; \
    v2f hl = {hv4.x, hv4.y}; v2f hh = {hv4.z, hv4.w}; \
    acc0 += w0_##j##a * hl; acc0 += w0_##j##b * hh; \
    acc1 += w1_##j##a * hl; acc1 += w1_##j##b * hh; \
    acc2 += w2_##j##a * hl; acc2 += w2_##j##b * hh; \
    acc3 += w3_##j##a * hl; acc3 += w3_##j##b * hh; }

__global__ void
__attribute__((amdgpu_flat_work_group_size(512, 512), amdgpu_waves_per_eu(2, 2)))
lstm2_rec(
    const float* __restrict__ xg0, const float* __restrict__ xg1,
    const float* __restrict__ Whh0, const float* __restrict__ Whh1,
    float* __restrict__ h0s, float* __restrict__ c0s,
    float* __restrict__ h1s, float* __restrict__ c1s,
    float* __restrict__ h1c, float* __restrict__ p_out,
    int phase, int nch, int Tc) {
    int layer = blockIdx.y;
    if (layer == 0 && phase >= nch) return;
    if (layer == 1 && phase == 0) return;
    const float* __restrict__ xg  = layer ? xg1 : xg0;
    const float* __restrict__ Whh = layer ? Whh1 : Whh0;
    float* hs = layer ? h1s : h0s;
    float* cs = layer ? c1s : c0s;
    int t_start = (layer ? (phase - 1) : phase) * Tc;

    int b = blockIdx.x, t = threadIdx.x;
    int g = t >> 2, kq = t & 3;
    __shared__ __align__(16) float hb[2][160];   // 4 quarters x 36-float swizzled rows

    LOADW_R(0) LOADW_R(1) LOADW_R(2) LOADW_R(3)
    KEEPW_R(0) KEEPW_R(1) KEEPW_R(2) KEEPW_R(3)

    float c = 0.f;
    float xc0 = 0.f, xc1 = 0.f, xc2 = 0.f, xc3 = 0.f;
    const float* xgb = xg + (size_t)b * Tc * 512;
    if (kq == 0) {
        c = cs[b * 128 + g];
        xc0 = xgb[g]; xc1 = xgb[g + 128]; xc2 = xgb[g + 256]; xc3 = xgb[g + 384];
    }
    if (t < 128) hb[0][(t >> 5) * 36 + (t & 31)] = hs[b * 128 + t];
    __syncthreads();

    int cur = 0;
    float h = 0.f;
#pragma unroll 1
    for (int tl = 0; tl < Tc; tl++) {
        float xn0 = 0.f, xn1 = 0.f, xn2 = 0.f, xn3 = 0.f;
        if (kq == 0 && tl + 1 < Tc) {
            const float* xr = &xgb[(size_t)(tl + 1) * 512];
            xn0 = xr[g]; xn1 = xr[g + 128]; xn2 = xr[g + 256]; xn3 = xr[g + 384];
        }
        v2f acc0 = {0.f, 0.f}, acc1 = {0.f, 0.f}, acc2 = {0.f, 0.f}, acc3 = {0.f, 0.f};
        const float4* h4 = (const float4*)&hb[cur][kq * 36];
        DOTJ(0) DOTJ(1) DOTJ(2) DOTJ(3) DOTJ(4) DOTJ(5) DOTJ(6) DOTJ(7)
        float a0 = quad_sum(acc0.x + acc0.y);
        float a1 = quad_sum(acc1.x + acc1.y);
        float a2 = quad_sum(acc2.x + acc2.y);
        float a3 = quad_sum(acc3.x + acc3.y);
        if (kq == 0) {
            float gi = a0 + xc0, gf = a1 + xc1, gg = a2 + xc2, go = a3 + xc3;
            c = sigmoidf_(gf) * c + sigmoidf_(gi) * tanhf_(gg);
            h = sigmoidf_(go) * tanhf_(c);
            hb[cur ^ 1][(g >> 5) * 36 + (g & 31)] = h;
            if (layer == 0) {
                h1c[(size_t)(b * Tc + tl) * 128 + g] = h;
            } else if (t_start + tl == TT - 1) {
                p_out[b * 128 + g] = leaky(h);
            }
            xc0 = xn0; xc1 = xn1; xc2 = xn2; xc3 = xn3;
        }
        __syncthreads();
        cur ^= 1;
    }
    if (kq == 0) { cs[b * 128 + g] = c; hs[b * 128 + g] = h; }
}

// ---------------- Head part 1: per-row i, everything up to n + precomputes ---------
__global__ __launch_bounds__(256) void head1_kernel(
    const float* __restrict__ x_message, const float* __restrict__ pseudo,
    const float* __restrict__ p_out,
    const float* __restrict__ Wum, const float* __restrict__ Wvm,
    const float* __restrict__ Wup, const float* __restrict__ Wvp,
    const float* __restrict__ Wpe, const float* __restrict__ bpe,
    const float* __restrict__ Whyb, const float* __restrict__ bhyb,
    const float* __restrict__ Wact, const float* __restrict__ bact,
    const float* __restrict__ Winact, const float* __restrict__ binact,
    const float* __restrict__ Wphin, const float* __restrict__ Won,
    const float* __restrict__ Weo,
    float* __restrict__ st_out, float* __restrict__ n_out, float* __restrict__ wnn_out,
    float* __restrict__ R_out, float* __restrict__ S_out,
    float* __restrict__ P_out, float* __restrict__ Q_out,
    float* __restrict__ A_out, float* __restrict__ B_out,
    float* __restrict__ d_out) {
    int i = blockIdx.x, tid = threadIdx.x;
    __shared__ float mc[769];
    __shared__ float pcp[128];
    __shared__ float um[128], vm[128], up[128], vp[128];
    __shared__ float hyb[256], nsh[256];
    __shared__ float red[4];
    __shared__ float sred[2][2];
    __shared__ float st_sh, hp0_sh, hp1_sh, wpol_sh, norm_sh;

    float s = 0.f;
    for (int q = tid; q < 768; q += 256) s += x_message[i * 768 + q];
    s = waveRedSum(s);
    if ((tid & 63) == 0) red[tid >> 6] = s;
    __syncthreads();
    if (tid == 0) {
        float tot = red[0] + red[1] + red[2] + red[3];
        float st = (tot == 0.f) ? 1.f : 0.f;
        st_sh = st; st_out[i] = st;
    }
    __syncthreads();
    float st = st_sh;
    for (int q = tid; q < 768; q += 256)
        mc[q] = (st == 1.f) ? pseudo[q] : x_message[i * 768 + q];
    if (tid == 0) mc[768] = st;
    if (tid < 128) pcp[tid] = p_out[i * 128 + tid];
    __syncthreads();

    if (tid < 128) {
        int d = tid;
        float a0 = 0.f;
        for (int q = 0; q < 769; q++) a0 += mc[q] * Wum[q * 128 + d];
        um[d] = leaky(a0);
        float a1 = 0.f;
        for (int q = 0; q < 128; q++) a1 += pcp[q] * Wup[q * 128 + d];
        a1 += st * Wup[128 * 128 + d];
        up[d] = leaky(a1);
    } else {
        int d = tid - 128;
        float a0 = 0.f;
        for (int q = 0; q < 769; q++) a0 += mc[q] * Wvm[q * 128 + d];
        vm[d] = leaky(a0);
        float a1 = 0.f;
        for (int q = 0; q < 128; q++) a1 += pcp[q] * Wvp[q * 128 + d];
        a1 += st * Wvp[128 * 128 + d];
        vp[d] = leaky(a1);
    }
    __syncthreads();

    float t0 = 0.f, t1 = 0.f;
    if (tid < 128) {
        int d = tid;
        float um_d = um[d], vp_d = vp[d], uv = um_d * vp_d;
        t0 = um_d * Wpe[d] + uv * Wpe[128 + d] + vp_d * Wpe[256 + d];
        t1 = um_d * Wpe[384 + d] + uv * Wpe[384 + 128 + d] + vp_d * Wpe[384 + 256 + d];
    }
    t0 = waveRedSum(t0); t1 = waveRedSum(t1);
    if (tid < 128 && (tid & 63) == 0) { sred[0][tid >> 6] = t0; sred[1][tid >> 6] = t1; }
    __syncthreads();
    if (tid == 0) {
        float z0 = sred[0][0] + sred[0][1] + bpe[0];
        float z1 = sred[1][0] + sred[1][1] + bpe[1];
        float mx = fmaxf(z0, z1);
        float e0 = __expf(z0 - mx), e1 = __expf(z1 - mx);
        float inv = 1.f / (e0 + e1);
        float h0 = e0 * inv, h1 = e1 * inv;
        d_out[236 + i * 2 + 0] = h0; d_out[236 + i * 2 + 1] = h1;
        hp0_sh = h0; hp1_sh = h1;
        float sgn = (z1 > z0) ? 1.f : ((z1 < z0) ? -1.f : 0.f);
        wpol_sh = (st == 0.f) ? sgn : 0.f;
    }
    __syncthreads();

    {
        float acc = bhyb[tid];
        const float* Wr = Whyb + tid * 384;
        for (int q = 0; q < 128; q++) {
            float upq = up[q], vmq = vm[q];
            acc += upq * Wr[q] + (upq + vmq) * Wr[128 + q] + vmq * Wr[256 + q];
        }
        hyb[tid] = leaky(acc);
    }
    __syncthreads();

    {
        float hp0 = hp0_sh, hp1 = hp1_sh;
        float aa = bact[tid];
        float ai = binact[tid];
        const float* Wr = Wact + tid * 258;
        const float* Wr2 = Winact + tid * 256;
        for (int q = 0; q < 256; q++) { float h = hyb[q]; aa += h * Wr[q]; ai += h * Wr2[q]; }
        aa += hp0 * Wr[256] + hp1 * Wr[257];
        float nv = leaky(aa * (1.f - st) + ai * st);
        nsh[tid] = nv; n_out[i * 256 + tid] = nv;
    }
    __syncthreads();

    float nv = nsh[tid];
    float ssum = waveRedSum(nv * nv);
    if ((tid & 63) == 0) red[tid >> 6] = ssum;
    __syncthreads();
    if (tid == 0) norm_sh = fmaxf(sqrtf(red[0] + red[1] + red[2] + red[3]), 1e-8f);
    __syncthreads();
    wnn_out[i * 256 + tid] = wpol_sh * nv / norm_sh;

    if (tid < 192) {
        float r = 0.f, sc = 0.f;
        for (int q = 0; q < 256; q++) {
            float nq = nsh[q];
            r += nq * Wphin[q * 192 + tid];
            sc += nq * Wphin[(256 + q) * 192 + tid];
        }
        R_out[i * 192 + tid] = r; S_out[i * 192 + tid] = sc;
    }
    {
        float pa = 0.f, qa = 0.f, aa = 0.f, ba = 0.f;
        for (int q = 0; q < 256; q++) {
            float nq = nsh[q];
            pa += nq * Won[q * 256 + tid];
            qa += nq * Won[(256 + q) * 256 + tid];
            aa += nq * Weo[(256 + q) * 256 + tid];
            ba += nq * Weo[(512 + q) * 256 + tid];
        }
        P_out[i * 256 + tid] = pa; Q_out[i * 256 + tid] = qa;
        A_out[i * 256 + tid] = aa; B_out[i * 256 + tid] = ba;
    }
}

// ---------------- l_ort via Gram trick --------------------------------------------
__global__ __launch_bounds__(128) void lort_kernel(
    const float* __restrict__ Wum, const float* __restrict__ Wvm,
    const float* __restrict__ Wup, const float* __restrict__ Wvp,
    float* __restrict__ lort) {
    int k = blockIdx.x, l = threadIdx.x, which = blockIdx.y;
    const float* Am = which ? Wup : Wum;
    const float* Bm = which ? Wvp : Wvm;
    int Rr = which ? 129 : 769;
    float g1 = 0.f, g2 = 0.f;
    for (int m = 0; m < Rr; m++) {
        g1 += Am[m * 128 + k] * Am[m * 128 + l];
        g2 += Bm[m * 128 + k] * Bm[m * 128 + l];
    }
    float p = waveRedSum(g1 * g2);
    if ((l & 63) == 0) atomicAdd(&lort[which], p);
}

// ---------------- phi(i,j) = leaky(R[j]+S[i]) . aphi  (stored column-major) --------
__global__ __launch_bounds__(128) void phi_kernel(
    const float* __restrict__ R, const float* __restrict__ S,
    const float* __restrict__ aphi, float* __restrict__ phi_cm) {
    int j = blockIdx.x, tid = threadIdx.x;
    __shared__ float rj[192], ap[192];
    for (int q = tid; q < 192; q += 128) { rj[q] = R[j * 192 + q]; ap[q] = aphi[q]; }
    __syncthreads();
    if (tid < NN) {
        const float* Si = S + tid * 192;
        float acc = 0.f;
        for (int d = 0; d < 192; d++) acc += leaky(rj[d] + Si[d]) * ap[d];
        phi_cm[j * NN + tid] = acc;
    }
}

// ---------------- double group-softmax over rows, per column ----------------------
__global__ __launch_bounds__(128) void alpha_kernel(
    const float* __restrict__ phi_cm, const float* __restrict__ stv,
    float* __restrict__ w0_cm, float* __restrict__ w1_cm) {
    int j = blockIdx.x, tid = threadIdx.x;
    __shared__ float sm[2][2], ssum[2][2];
    bool act = tid < NN;
    float sti = act ? stv[tid] : -1.f;
    float v = act ? phi_cm[j * NN + tid] : 0.f;
    float m0 = (sti == 0.f) ? v : -3.0e38f;
    float m1 = (sti == 1.f) ? v : -3.0e38f;
    float M0 = waveRedMax(m0), M1 = waveRedMax(m1);
    if ((tid & 63) == 0) { sm[tid >> 6][0] = M0; sm[tid >> 6][1] = M1; }
    __syncthreads();
    M0 = fmaxf(sm[0][0], sm[1][0]); M1 = fmaxf(sm[0][1], sm[1][1]);
    float e = 0.f;
    if (act) e = __expf(v - ((sti == 0.f) ? M0 : M1));
    float e0 = (sti == 0.f) ? e : 0.f, e1 = (sti == 1.f) ? e : 0.f;
    float S0 = waveRedSum(e0), S1 = waveRedSum(e1);
    if ((tid & 63) == 0) { ssum[tid >> 6][0] = S0; ssum[tid >> 6][1] = S1; }
    __syncthreads();
    S0 = ssum[0][0] + ssum[1][0]; S1 = ssum[0][1] + ssum[1][1];
    if (act) {
        float alpha = e / ((sti == 0.f) ? S0 : S1);
        w0_cm[j * NN + tid] = sti * alpha;
        w1_cm[j * NN + tid] = (1.f - sti) * alpha;
    }
}

// ---------------- per-row weighted sums over j ------------------------------------
__global__ __launch_bounds__(256) void qsum_kernel(
    const float* __restrict__ P, const float* __restrict__ Q, const float* __restrict__ Ab,
    const float* __restrict__ w0_cm, const float* __restrict__ w1_cm,
    float* __restrict__ qs0, float* __restrict__ qs1,
    float* __restrict__ as0, float* __restrict__ as1,
    float* __restrict__ ws0, float* __restrict__ ws1) {
    int i = blockIdx.x, d = threadIdx.x;
    float Qd = Q[i * 256 + d];
    float q0 = 0.f, q1 = 0.f, a0 = 0.f, a1 = 0.f, s0 = 0.f, s1 = 0.f;
    for (int jj = 0; jj < NN; jj++) {
        float w0 = w0_cm[jj * NN + i], w1 = w1_cm[jj * NN + i];
        float pq = leaky(P[jj * 256 + d] + Qd);
        float av = Ab[jj * 256 + d];
        q0 += w0 * pq; q1 += w1 * pq;
        a0 += w0 * av; a1 += w1 * av;
        s0 += w0; s1 += w1;
    }
    qs0[i * 256 + d] = q0; qs1[i * 256 + d] = q1;
    as0[i * 256 + d] = a0; as1[i * 256 + d] = a1;
    if (d == 0) { ws0[i] = s0; ws1[i] = s1; }
}

// ---------------- hm0/hm1, output head, y_hat -------------------------------------
__global__ __launch_bounds__(256) void hm_out_kernel(
    const float* __restrict__ qs0, const float* __restrict__ qs1,
    const float* __restrict__ as0, const float* __restrict__ as1,
    const float* __restrict__ ws0, const float* __restrict__ ws1,
    const float* __restrict__ Bb, const float* __restrict__ nbuf,
    const float* __restrict__ Weo, const float* __restrict__ Wi,
    const float* __restrict__ bi, float* __restrict__ d_out) {
    int i = blockIdx.x, d = threadIdx.x;
    __shared__ float q0sh[256], q1sh[256];
    __shared__ float r0[4], r1[4];
    q0sh[d] = qs0[i * 256 + d]; q1sh[d] = qs1[i * 256 + d];
    __syncthreads();
    float Bd = Bb[i * 256 + d];
    float h0 = as0[i * 256 + d] + ws0[i] * Bd;
    float h1 = as1[i * 256 + d] + ws1[i] * Bd;
    for (int k = 0; k < 256; k++) {
        float w = Weo[k * 256 + d];
        h0 += q0sh[k] * w; h1 += q1sh[k] * w;
    }
    h0 = leaky(h0); h1 = leaky(h1);
    float nd = nbuf[i * 256 + d];
    const float* Wii = Wi + (size_t)i * 1536;
    float l0 = nd * Wii[d * 2] + h0 * Wii[(256 + d) * 2] + h1 * Wii[(512 + d) * 2];
    float l1 = nd * Wii[d * 2 + 1] + h0 * Wii[(256 + d) * 2 + 1] + h1 * Wii[(512 + d) * 2 + 1];
    l0 = waveRedSum(l0); l1 = waveRedSum(l1);
    if ((d & 63) == 0) { r0[d >> 6] = l0; r1[d >> 6] = l1; }
    __syncthreads();
    if (d == 0) {
        float z0 = r0[0] + r0[1] + r0[2] + r0[3] + bi[i * 2 + 0];
        float z1 = r1[0] + r1[1] + r1[2] + r1[3] + bi[i * 2 + 1];
        float mx = fmaxf(z0, z1);
        float e0 = __expf(z0 - mx), e1 = __expf(z1 - mx);
        float inv = 1.f / (e0 + e1);
        d_out[i * 2 + 0] = e0 * inv;
        d_out[i * 2 + 1] = e1 * inv;
    }
}

// ---------------- l_pol + l_ort finalize ------------------------------------------
__global__ __launch_bounds__(256) void pol_kernel(
    const float* __restrict__ wnn, const float* __restrict__ lort,
    float* __restrict__ d_out) {
    int d = threadIdx.x;
    __shared__ float red[4];
    float s = 0.f;
    for (int i = 0; i < NN; i++) s += wnn[i * 256 + d];
    float p = waveRedSum(s * s);
    if ((d & 63) == 0) red[d >> 6] = p;
    __syncthreads();
    if (d == 0) {
        d_out[473] = red[0] + red[1] + red[2] + red[3];
        d_out[472] = sqrtf(lort[0]) + sqrtf(lort[1]);
    }
}

extern "C" void kernel_launch(void* const* d_in, const int* in_sizes, int n_in,
                              void* d_out_v, int out_size, void* d_ws, size_t ws_size,
                              hipStream_t stream) {
    (void)in_sizes; (void)n_in; (void)out_size;
    const float* x        = (const float*)d_in[0];
    const float* x_msg    = (const float*)d_in[1];
    const float* pseudo   = (const float*)d_in[2];
    const float* Wih0     = (const float*)d_in[3];
    const float* Whh0     = (const float*)d_in[4];
    const float* bih0     = (const float*)d_in[5];
    const float* bhh0     = (const float*)d_in[6];
    const float* Wih1     = (const float*)d_in[7];
    const float* Whh1     = (const float*)d_in[8];
    const float* bih1     = (const float*)d_in[9];
    const float* bhh1     = (const float*)d_in[10];
    const float* Wum      = (const float*)d_in[11];
    const float* Wvm      = (const float*)d_in[12];
    const float* Wup      = (const float*)d_in[13];
    const float* Wvp      = (const float*)d_in[14];
    const float* Wpe      = (const float*)d_in[15];
    const float* bpe      = (const float*)d_in[16];
    const float* Whyb     = (const float*)d_in[17];
    const float* bhyb     = (const float*)d_in[18];
    const float* Wact     = (const float*)d_in[19];
    const float* bact     = (const float*)d_in[20];
    const float* Winact   = (const float*)d_in[21];
    const float* binact   = (const float*)d_in[22];
    const float* Wphin    = (const float*)d_in[23];
    const float* aphi     = (const float*)d_in[24];
    const float* Won      = (const float*)d_in[25];
    const float* Weo      = (const float*)d_in[26];
    const float* Wi       = (const float*)d_in[27];
    const float* bi       = (const float*)d_in[28];
    float* out = (float*)d_out_v;

    char* wsb = (char*)d_ws;
    size_t off = 0;
    auto alloc = [&](size_t nfloats) {
        float* p = (float*)(wsb + off);
        off += ((nfloats * 4 + 255) / 256) * 256;
        return p;
    };
    float* h0s   = alloc(NN * 128);
    float* c0s   = alloc(NN * 128);
    float* h1s   = alloc(NN * 128);
    float* c1s   = alloc(NN * 128);
    float* lort  = alloc(2);
    float* stb   = alloc(NN);
    float* p_out = alloc(NN * 128);
    float* nbuf  = alloc(NN * 256);
    float* wnn   = alloc(NN * 256);
    float* Rb    = alloc(NN * 192);
    float* Sb    = alloc(NN * 192);
    float* Pb    = alloc(NN * 256);
    float* Qb    = alloc(NN * 256);
    float* Ab    = alloc(NN * 256);
    float* Bb    = alloc(NN * 256);
    float* qs0   = alloc(NN * 256);
    float* qs1   = alloc(NN * 256);
    float* as0   = alloc(NN * 256);
    float* as1   = alloc(NN * 256);
    float* ws0   = alloc(NN);
    float* ws1   = alloc(NN);
    float* phicm = alloc(NN * NN);
    float* w0cm  = alloc(NN * NN);
    float* w1cm  = alloc(NN * NN);

    size_t remain = (ws_size > off) ? (ws_size - off) : 0;
    int Tc = 2048;
    // need xg0 + xg1 (NN*Tc*512 each) + h1c (NN*Tc*128)
    while (Tc > 64 && (size_t)NN * Tc * (512 + 512 + 128) * 4 > remain) Tc >>= 1;
    float* xg0 = alloc((size_t)NN * Tc * 512);
    float* xg1 = alloc((size_t)NN * Tc * 512);
    float* h1c = alloc((size_t)NN * Tc * 128);
    int lgTc = __builtin_ctz(Tc);

    hipMemsetAsync(h0s, 0, (size_t)4 * NN * 128 * sizeof(float), stream); // h0s..c1s contiguous
    hipMemsetAsync(lort, 0, 2 * sizeof(float), stream);

    int nch = TT / Tc;
    dim3 gg((NN * Tc) / 64, 8);
    // prologue: xg0 for chunk 0
    xg_gemm<64><<<gg, 256, 0, stream>>>(x, Wih0, bih0, bhh0, xg0, TT, 0, lgTc);
    for (int p = 0; p <= nch; p++) {
        lstm2_rec<<<dim3(NN, 2), 512, 0, stream>>>(xg0, xg1, Whh0, Whh1,
                                                   h0s, c0s, h1s, c1s,
                                                   h1c, p_out, p, nch, Tc);
        if (p < nch)
            xg_gemm<128><<<gg, 256, 0, stream>>>(h1c, Wih1, bih1, bhh1, xg1, Tc, 0, lgTc);
        if (p + 1 < nch)
            xg_gemm<64><<<gg, 256, 0, stream>>>(x, Wih0, bih0, bhh0, xg0, TT, (p + 1) * Tc, lgTc);
    }
    head1_kernel<<<NN, 256, 0, stream>>>(x_msg, pseudo, p_out, Wum, Wvm, Wup, Wvp,
                                         Wpe, bpe, Whyb, bhyb, Wact, bact, Winact, binact,
                                         Wphin, Won, Weo,
                                         stb, nbuf, wnn, Rb, Sb, Pb, Qb, Ab, Bb, out);
    lort_kernel<<<dim3(128, 2), 128, 0, stream>>>(Wum, Wvm, Wup, Wvp, lort);
    phi_kernel<<<NN, 128, 0, stream>>>(Rb, Sb, aphi, phicm);
    alpha_kernel<<<NN, 128, 0, stream>>>(phicm, stb, w0cm, w1cm);
    qsum_kernel<<<NN, 256, 0, stream>>>(Pb, Qb, Ab, w0cm, w1cm, qs0, qs1, as0, as1, ws0, ws1);
    hm_out_kernel<<<NN, 256, 0, stream>>>(qs0, qs1, as0, as1, ws0, ws1, Bb, nbuf, Weo, Wi, bi, out);
    pol_kernel<<<1, 256, 0, stream>>>(wnn, lort, out);
}